// Round 1
// baseline (178.002 us; speedup 1.0000x reference)
//
#include <hip/hip_runtime.h>

// Kill FMA contraction globally: we must match numpy/XLA's separate mul+add
// rounding bit-for-bit, or borderline mask bits flip and the compaction shifts.
#pragma clang fp contract(off)

namespace {

constexpr int S = 64;
// linspace(0,1,64): t_i = i * fl(1/63). Note fl(63*fl(1/63)) == 1.0f exactly,
// so this matches both the clamped (np) and unclamped (jnp) endpoint variants.
constexpr float DELTA = 1.0f / 63.0f;

__device__ __forceinline__ void ray_nearfar(
    float ox, float oy, float oz,
    float dx, float dy, float dz,
    float R, float& nr, float& fr) {
  float ix = 1.0f / ((dx == 0.0f) ? 1e-6f : dx);
  float iy = 1.0f / ((dy == 0.0f) ? 1e-6f : dy);
  float iz = 1.0f / ((dz == 0.0f) ? 1e-6f : dz);
  float mR = -R;
  float ax = (mR - ox) * ix, bx = (R - ox) * ix;
  float ay = (mR - oy) * iy, by = (R - oy) * iy;
  float az = (mR - oz) * iz, bz = (R - oz) * iz;
  nr = fmaxf(fmaxf(fminf(ax, bx), fminf(ay, by)), fminf(az, bz));
  fr = fminf(fminf(fmaxf(ax, bx), fmaxf(ay, by)), fmaxf(az, bz));
}

// Kernel A: one thread per ray. Count valid samples; exclusive scan within
// the 256-thread block; emit per-ray local offset L[r] and per-block sum.
__global__ __launch_bounds__(256) void k_count(
    const float* __restrict__ ro, const float* __restrict__ rd,
    const float* __restrict__ radii,
    int* __restrict__ L, int* __restrict__ blockSums, int N) {
  int r = blockIdx.x * 256 + threadIdx.x;
  int cnt = 0;
  if (r < N) {
    float R = radii[0];
    float ox = ro[3 * r], oy = ro[3 * r + 1], oz = ro[3 * r + 2];
    float dx = rd[3 * r], dy = rd[3 * r + 1], dz = rd[3 * r + 2];
    float nr, fr;
    ray_nearfar(ox, oy, oz, dx, dy, dz, R, nr, fr);
    float f = fr - nr;
    for (int s = 0; s < S; ++s) {
      float dep = nr + f * ((float)s * DELTA);
      float sx = (ox + dx * dep) / R;
      float sy = (oy + dy * dep) / R;
      float sz = (oz + dz * dep) / R;
      float nm = sqrtf((sx * sx + sy * sy) + sz * sz);
      cnt += (nm <= 1.0f) ? 1 : 0;
    }
  }
  __shared__ int sm[256];
  sm[threadIdx.x] = cnt;
  __syncthreads();
  for (int off = 1; off < 256; off <<= 1) {
    int t = (threadIdx.x >= off) ? sm[threadIdx.x - off] : 0;
    __syncthreads();
    sm[threadIdx.x] += t;
    __syncthreads();
  }
  if (r < N) L[r] = sm[threadIdx.x] - cnt;  // exclusive within block
  if (threadIdx.x == 255) blockSums[blockIdx.x] = sm[255];
}

// Kernel B: single block scans the (<=1024) block sums -> exclusive block
// offsets, total valid count (int to ws, float to d_out tail).
__global__ __launch_bounds__(1024) void k_scan(
    const int* __restrict__ blockSums, int* __restrict__ blockOff,
    int* __restrict__ total, float* __restrict__ out_nv, int nb) {
  __shared__ int sm[1024];
  int x = (threadIdx.x < nb) ? blockSums[threadIdx.x] : 0;
  sm[threadIdx.x] = x;
  __syncthreads();
  for (int off = 1; off < 1024; off <<= 1) {
    int t = (threadIdx.x >= off) ? sm[threadIdx.x - off] : 0;
    __syncthreads();
    sm[threadIdx.x] += t;
    __syncthreads();
  }
  if (threadIdx.x < nb) blockOff[threadIdx.x] = sm[threadIdx.x] - x;
  if (threadIdx.x == 1023) {
    *total = sm[1023];
    out_nv[0] = (float)sm[1023];
  }
}

// Kernel D: one wave per ray, lane = sample index. Ballot reconstructs the
// ray's 64-bit mask; lane rank within mask gives the stable-partition dest.
__global__ __launch_bounds__(256) void k_scatter(
    const float* __restrict__ ro, const float* __restrict__ rd,
    const float* __restrict__ radii,
    const int* __restrict__ L, const int* __restrict__ blockOff,
    const int* __restrict__ total,
    float* __restrict__ out, int N) {
  int m = blockIdx.x * 256 + threadIdx.x;
  int M = N * S;
  if (m >= M) return;  // wave-uniform: M % 64 == 0
  int s = m & 63;
  int r = m >> 6;
  float R = radii[0];
  float ox = ro[3 * r], oy = ro[3 * r + 1], oz = ro[3 * r + 2];
  float dx = rd[3 * r], dy = rd[3 * r + 1], dz = rd[3 * r + 2];
  float nr, fr;
  ray_nearfar(ox, oy, oz, dx, dy, dz, R, nr, fr);
  float f = fr - nr;
  float dep = nr + f * ((float)s * DELTA);
  float sx = (ox + dx * dep) / R;
  float sy = (oy + dy * dep) / R;
  float sz = (oz + dz * dep) / R;
  float nm = sqrtf((sx * sx + sy * sy) + sz * sz);
  bool bit = (nm <= 1.0f);
  unsigned long long msk = __ballot(bit);
  int below = __popcll(msk & ((1ull << s) - 1ull));
  int Vr = L[r] + blockOff[r >> 8];  // global # of valid elems before this ray
  int nv = *total;
  // valid -> compact front; invalid -> tail, both stable.
  int dest = bit ? (Vr + below)
                 : (nv + ((m & ~63) - Vr) + (s - below));
  // deltas = diff(depth, prepend=near): replicate exactly.
  float prev = (s == 0) ? nr : (nr + f * ((float)(s - 1) * DELTA));
  float del = dep - prev;

  float* out_s  = out + M;       // samples_c [M,3]
  float* out_d  = out + 4 * M;   // depth_c   [M]
  float* out_dl = out + 5 * M;   // deltas_c  [M,1]
  float* out_b  = out + 6 * M;   // boundary  [M]
  out[dest] = (float)r;
  out_s[3 * dest + 0] = sx;
  out_s[3 * dest + 1] = sy;
  out_s[3 * dest + 2] = sz;
  out_d[dest] = dep;
  out_dl[dest] = del;
  // boundary: first valid sample of a ray (handles j==0 too); tail = false.
  out_b[dest] = (bit && below == 0) ? 1.0f : 0.0f;
}

}  // namespace

extern "C" void kernel_launch(void* const* d_in, const int* in_sizes, int n_in,
                              void* d_out, int out_size, void* d_ws, size_t ws_size,
                              hipStream_t stream) {
  const float* ro = (const float*)d_in[0];
  const float* rd = (const float*)d_in[1];
  const float* radii = (const float*)d_in[2];
  int N = in_sizes[0] / 3;           // 262144
  int M = N * S;                     // 16777216
  int nbA = (N + 255) / 256;         // 1024

  int* wsI = (int*)d_ws;
  int* L = wsI;                      // N ints
  int* blockSums = wsI + N;          // nbA ints
  int* blockOff = blockSums + nbA;   // nbA ints
  int* total = blockOff + nbA;       // 1 int

  float* out = (float*)d_out;
  float* out_nv = out + (size_t)7 * (size_t)M;  // num_valid slot

  k_count<<<nbA, 256, 0, stream>>>(ro, rd, radii, L, blockSums, N);
  k_scan<<<1, 1024, 0, stream>>>(blockSums, blockOff, total, out_nv, nbA);
  int nbD = (M + 255) / 256;
  k_scatter<<<nbD, 256, 0, stream>>>(ro, rd, radii, L, blockOff, total, out, N);
}